// Round 1
// baseline (793.106 us; speedup 1.0000x reference)
//
#include <hip/hip_runtime.h>
#include <math.h>

// DenseCRF mean-field on MI355X. N=9216 pixels, C=21 classes, 5 iterations.
// Bilateral kernel recomputed (fused) each iteration: cheaper than reading a
// stored 340MB K matrix from HBM. Smoothness kernel = exact separable conv.

#define NN 9216
#define CC 21
#define HH 96
#define WW 96
#define CP 24            // padded channel stride (float4-friendly)
#define JS 16            // j-range splits (for grid size)
#define NJ (NN / JS)     // 576 j's per split
#define TJ 64            // j tile staged in LDS

// ---------------- features: [n][8] = fy,fx,fr,fg,fb, -0.5*||f||^2, 0,0 ----
__global__ __launch_bounds__(256) void feat_kernel(const float* __restrict__ x,
                                                   float* __restrict__ feat) {
    int n = blockIdx.x * 256 + threadIdx.x;
    int y = n / WW, xx = n - y * WW;
    float fy = (float)y * (1.0f / 30.0f);
    float fx = (float)xx * (1.0f / 30.0f);
    float fr = x[0 * NN + n] * 10.0f;
    float fg = x[1 * NN + n] * 10.0f;
    float fb = x[2 * NN + n] * 10.0f;
    float S = fy * fy + fx * fx + fr * fr + fg * fg + fb * fb;
    float4* f4 = (float4*)(feat + (size_t)n * 8);
    f4[0] = make_float4(fy, fx, fr, fg);
    f4[1] = make_float4(fb, -0.5f * S, 0.0f, 0.0f);
}

// ---------------- initial softmax ----------------------------------------
__global__ __launch_bounds__(256) void init_kernel(const float* __restrict__ yhat,
                                                   float* __restrict__ unary,
                                                   float* __restrict__ out_nc,
                                                   float* __restrict__ out_cn) {
    int n = blockIdx.x * 256 + threadIdx.x;
    float u[CC], p[CC];
    float m = -1e30f;
#pragma unroll
    for (int c = 0; c < CC; c++) { u[c] = yhat[c * NN + n]; m = fmaxf(m, u[c]); }
    float s = 0.0f;
#pragma unroll
    for (int c = 0; c < CC; c++) { p[c] = __expf(u[c] - m); s += p[c]; }
    float inv = 1.0f / s;
#pragma unroll
    for (int c = 0; c < CC; c++) p[c] *= inv;
#pragma unroll
    for (int c = 0; c < CC; c++) {
        unary[n * CP + c] = u[c];
        out_nc[n * CP + c] = p[c];
        out_cn[c * NN + n] = p[c];
    }
#pragma unroll
    for (int c = CC; c < CP; c++) { unary[n * CP + c] = 0.0f; out_nc[n * CP + c] = 0.0f; }
}

// ---------------- bilateral message passing (the heavy kernel) ------------
// grid (36, JS): blockIdx.x picks 256 i's, blockIdx.y picks a j-range of NJ.
// Partial results go to part[blockIdx.y][i][CP].
__global__ __launch_bounds__(256) void bilateral_kernel(const float* __restrict__ feat,
                                                        const float* __restrict__ out_nc,
                                                        float* __restrict__ part) {
    __shared__ float sf[TJ * 8];
    __shared__ float so[TJ * CP];
    int tid = threadIdx.x;
    int i = blockIdx.x * 256 + tid;
    int j0base = blockIdx.y * NJ;

    float4 fA = *(const float4*)(feat + (size_t)i * 8);
    float2 fB = *(const float2*)(feat + (size_t)i * 8 + 4);
    float fyi = fA.x, fxi = fA.y, fri = fA.z, fgi = fA.w, fbi = fB.x, hSi = fB.y;

    float acc[CC];
#pragma unroll
    for (int c = 0; c < CC; c++) acc[c] = 0.0f;

    for (int t0 = 0; t0 < NJ; t0 += TJ) {
        int j0 = j0base + t0;
        __syncthreads();
        if (tid < TJ * 8 / 4) {  // 128 float4's of features
            ((float4*)sf)[tid] = ((const float4*)(feat + (size_t)j0 * 8))[tid];
        }
        for (int u = tid; u < TJ * CP / 4; u += 256) {  // 384 float4's of out
            ((float4*)so)[u] = ((const float4*)(out_nc + (size_t)j0 * CP))[u];
        }
        __syncthreads();
#pragma unroll 4
        for (int jj = 0; jj < TJ; jj++) {
            float4 gA = *(const float4*)(sf + jj * 8);
            float2 gB = *(const float2*)(sf + jj * 8 + 4);
            // -0.5*d2 = hSi + hSj + fi.fj
            float t = hSi + gB.y;
            t = fmaf(fyi, gA.x, t);
            t = fmaf(fxi, gA.y, t);
            t = fmaf(fri, gA.z, t);
            t = fmaf(fgi, gA.w, t);
            t = fmaf(fbi, gB.x, t);
            float k = __expf(t);
            const float* op = so + jj * CP;
#pragma unroll
            for (int c = 0; c < CC; c++) acc[c] = fmaf(k, op[c], acc[c]);
        }
    }
    float* dst = part + ((size_t)blockIdx.y * NN + i) * CP;
#pragma unroll
    for (int q = 0; q < 6; q++) {
        float a0 = (q * 4 + 0 < CC) ? acc[q * 4 + 0] : 0.0f;
        float a1 = (q * 4 + 1 < CC) ? acc[q * 4 + 1] : 0.0f;
        float a2 = (q * 4 + 2 < CC) ? acc[q * 4 + 2] : 0.0f;
        float a3 = (q * 4 + 3 < CC) ? acc[q * 4 + 3] : 0.0f;
        ((float4*)dst)[q] = make_float4(a0, a1, a2, a3);
    }
}

// ---------------- separable smoothness conv (exact, full width) -----------
__global__ __launch_bounds__(256) void smo_y_kernel(const float* __restrict__ src,
                                                    float* __restrict__ dst) {
    __shared__ float wt[2 * HH - 1];
    int tid = threadIdx.x;
    if (tid < 2 * HH - 1) {
        float d = (float)(tid - (HH - 1));
        wt[tid] = __expf(d * d * (-1.0f / 18.0f));
    }
    __syncthreads();
    int id = blockIdx.x * 256 + tid;       // c*NN + y*WW + x
    int c = id / NN;
    int rem = id - c * NN;
    int y = rem / WW;
    int x = rem - y * WW;
    const float* s = src + (size_t)c * NN + x;
    float a = 0.0f;
    for (int yp = 0; yp < HH; yp++) a = fmaf(wt[yp - y + (HH - 1)], s[yp * WW], a);
    dst[id] = a;
}

__global__ __launch_bounds__(256) void smo_x_kernel(const float* __restrict__ src,
                                                    float* __restrict__ dst) {
    __shared__ float wt[2 * HH - 1];
    int tid = threadIdx.x;
    if (tid < 2 * HH - 1) {
        float d = (float)(tid - (HH - 1));
        wt[tid] = __expf(d * d * (-1.0f / 18.0f));
    }
    __syncthreads();
    int id = blockIdx.x * 256 + tid;
    int c = id / NN;
    int rem = id - c * NN;
    int y = rem / WW;
    int x = rem - y * WW;
    const float* s = src + (size_t)c * NN + y * WW;
    float a = 0.0f;
    for (int xp = 0; xp < WW; xp++) a = fmaf(wt[xp - x + (HH - 1)], s[xp], a);
    dst[id] = a;
}

// ---------------- reduce partials + mu transform + softmax ----------------
__global__ __launch_bounds__(256) void combine_kernel(const float* __restrict__ part,
                                                      const float* __restrict__ smo,
                                                      const float* __restrict__ mu,
                                                      float* __restrict__ unary,
                                                      float* __restrict__ out_nc,
                                                      float* __restrict__ out_cn) {
    __shared__ float muL[CC * CC];
    int tid = threadIdx.x;
    for (int u = tid; u < CC * CC; u += 256) muL[u] = mu[u];
    __syncthreads();
    int n = blockIdx.x * 256 + tid;
    float app[CP];
#pragma unroll
    for (int c = 0; c < CP; c++) app[c] = 0.0f;
    for (int k = 0; k < JS; k++) {
        const float4* p4 = (const float4*)(part + ((size_t)k * NN + n) * CP);
#pragma unroll
        for (int q = 0; q < 6; q++) {
            float4 v = p4[q];
            app[q * 4 + 0] += v.x;
            app[q * 4 + 1] += v.y;
            app[q * 4 + 2] += v.z;
            app[q * 4 + 3] += v.w;
        }
    }
    float pin[CC];
#pragma unroll
    for (int c = 0; c < CC; c++) pin[c] = 10.0f * app[c] + 3.0f * smo[c * NN + n];
    float pout[CC];
#pragma unroll
    for (int j = 0; j < CC; j++) pout[j] = 0.0f;
#pragma unroll
    for (int i2 = 0; i2 < CC; i2++) {
        float v = pin[i2];
#pragma unroll
        for (int j = 0; j < CC; j++) pout[j] = fmaf(v, muL[i2 * CC + j], pout[j]);
    }
    float u[CC], p[CC];
    float m = -1e30f;
#pragma unroll
    for (int c = 0; c < CC; c++) {
        u[c] = unary[n * CP + c] + pout[c];
        m = fmaxf(m, u[c]);
    }
    float s = 0.0f;
#pragma unroll
    for (int c = 0; c < CC; c++) { p[c] = __expf(u[c] - m); s += p[c]; }
    float inv = 1.0f / s;
#pragma unroll
    for (int c = 0; c < CC; c++) p[c] *= inv;
#pragma unroll
    for (int c = 0; c < CC; c++) {
        unary[n * CP + c] = u[c];
        out_nc[n * CP + c] = p[c];
        out_cn[c * NN + n] = p[c];
    }
}

extern "C" void kernel_launch(void* const* d_in, const int* in_sizes, int n_in,
                              void* d_out, int out_size, void* d_ws, size_t ws_size,
                              hipStream_t stream) {
    const float* x = (const float*)d_in[0];     // (3,96,96)
    const float* yhat = (const float*)d_in[1];  // (21,96,96)
    const float* mu = (const float*)d_in[2];    // (21,21)
    float* out = (float*)d_out;                 // (21,96,96) — used as out_cn
    float* ws = (float*)d_ws;

    float* feat   = ws;                         // 8*N      = 73728
    float* out_nc = ws + 73728;                 // 24*N     = 221184
    float* unary  = ws + 294912;                // 24*N
    float* smo    = ws + 516096;                // 21*N     = 193536
    float* tmp    = ws + 709632;                // 21*N
    float* part   = ws + 903168;                // JS*24*N  = 3538944

    feat_kernel<<<NN / 256, 256, 0, stream>>>(x, feat);
    init_kernel<<<NN / 256, 256, 0, stream>>>(yhat, unary, out_nc, out);

    for (int it = 0; it < 5; it++) {
        bilateral_kernel<<<dim3(NN / 256, JS), 256, 0, stream>>>(feat, out_nc, part);
        smo_y_kernel<<<CC * NN / 256, 256, 0, stream>>>(out, tmp);
        smo_x_kernel<<<CC * NN / 256, 256, 0, stream>>>(tmp, smo);
        combine_kernel<<<NN / 256, 256, 0, stream>>>(part, smo, mu, unary, out_nc, out);
    }
}

// Round 2
// 562.549 us; speedup vs baseline: 1.4098x; 1.4098x over previous
//
#include <hip/hip_runtime.h>
#include <math.h>

// DenseCRF mean-field on MI355X. N=9216 pixels, C=21 classes, 5 iterations.
// R2: occupancy fix — 2304 blocks (4x), per-wave j-quarter with LDS staging,
// cross-wave reduce. Features pre-scaled by 1/sqrt(ln2) so k = exp2f(dot).

#define NN 9216
#define CC 21
#define HH 96
#define WW 96
#define CP 24            // padded channel stride (float4-friendly)
#define JS 16            // j-range splits (part slices)
#define NJ (NN / JS)     // 576 j's per slice
#define NJQ (NJ / 4)     // 144 j's per wave
#define TJ 36            // j tile per wave staged in LDS

// ---------------- features: [n][8] = fy..fb (scaled by 1/(sig*sqrt(ln2))), -0.5*||f||^2
__global__ __launch_bounds__(256) void feat_kernel(const float* __restrict__ x,
                                                   float* __restrict__ feat) {
    int n = blockIdx.x * 256 + threadIdx.x;
    int y = n / WW, xx = n - y * WW;
    const float inv_sqrt_ln2 = 1.2011224087864498f;
    float sp = inv_sqrt_ln2 / 30.0f;
    float sc = inv_sqrt_ln2 * 10.0f;
    float fy = (float)y * sp;
    float fx = (float)xx * sp;
    float fr = x[0 * NN + n] * sc;
    float fg = x[1 * NN + n] * sc;
    float fb = x[2 * NN + n] * sc;
    float S = fy * fy + fx * fx + fr * fr + fg * fg + fb * fb;
    float4* f4 = (float4*)(feat + (size_t)n * 8);
    f4[0] = make_float4(fy, fx, fr, fg);
    f4[1] = make_float4(fb, -0.5f * S, 0.0f, 0.0f);
}

// ---------------- initial softmax ----------------------------------------
__global__ __launch_bounds__(256) void init_kernel(const float* __restrict__ yhat,
                                                   float* __restrict__ unary,
                                                   float* __restrict__ out_nc,
                                                   float* __restrict__ out_cn) {
    int n = blockIdx.x * 256 + threadIdx.x;
    float u[CC], p[CC];
    float m = -1e30f;
#pragma unroll
    for (int c = 0; c < CC; c++) { u[c] = yhat[c * NN + n]; m = fmaxf(m, u[c]); }
    float s = 0.0f;
#pragma unroll
    for (int c = 0; c < CC; c++) { p[c] = __expf(u[c] - m); s += p[c]; }
    float inv = 1.0f / s;
#pragma unroll
    for (int c = 0; c < CC; c++) p[c] *= inv;
#pragma unroll
    for (int c = 0; c < CC; c++) {
        unary[n * CP + c] = u[c];
        out_nc[n * CP + c] = p[c];
        out_cn[c * NN + n] = p[c];
    }
#pragma unroll
    for (int c = CC; c < CP; c++) { unary[n * CP + c] = 0.0f; out_nc[n * CP + c] = 0.0f; }
}

// ---------------- bilateral message passing (the heavy kernel) ------------
// grid (NN/64=144, JS=16). Block: 64 i's, 4 waves = 4 j-quarters of the
// block's j-slice. Per-tile LDS staging, final cross-wave LDS reduce.
__global__ __launch_bounds__(256, 8) void bilateral_kernel(const float* __restrict__ feat,
                                                           const float* __restrict__ out_nc,
                                                           float* __restrict__ part) {
    __shared__ float smem[4608];           // 18432 B: staging; reused for reduce
    float* sf = smem;                      // [4][TJ*8]   = 1152 floats
    float* so = smem + 4 * TJ * 8;         // [4][TJ*CP]  = 3456 floats

    int tid = threadIdx.x;
    int lane = tid & 63;
    int w = tid >> 6;
    int i = blockIdx.x * 64 + lane;
    int jbase = blockIdx.y * NJ;

    float4 fA = *(const float4*)(feat + (size_t)i * 8);
    float2 fB = *(const float2*)(feat + (size_t)i * 8 + 4);
    float fyi = fA.x, fxi = fA.y, fri = fA.z, fgi = fA.w, fbi = fB.x, hSi = fB.y;

    float acc[CC];
#pragma unroll
    for (int c = 0; c < CC; c++) acc[c] = 0.0f;

    const float* sfw = sf + w * (TJ * 8);
    const float* sow = so + w * (TJ * CP);

    for (int t0 = 0; t0 < NJQ; t0 += TJ) {
        __syncthreads();
        // stage 4 regions: region rw holds TJ j's starting at jbase + rw*NJQ + t0
        for (int v = tid; v < 4 * TJ * 8 / 4; v += 256) {      // 288 float4
            int rw = v / (TJ * 2), u = v - rw * (TJ * 2);
            ((float4*)sf)[v] =
                ((const float4*)(feat + (size_t)(jbase + rw * NJQ + t0) * 8))[u];
        }
        for (int v = tid; v < 4 * TJ * CP / 4; v += 256) {     // 864 float4
            int rw = v / (TJ * 6), u = v - rw * (TJ * 6);
            ((float4*)so)[v] =
                ((const float4*)(out_nc + (size_t)(jbase + rw * NJQ + t0) * CP))[u];
        }
        __syncthreads();
#pragma unroll 4
        for (int jj = 0; jj < TJ; jj++) {
            float4 gA = *(const float4*)(sfw + jj * 8);
            float2 gB = *(const float2*)(sfw + jj * 8 + 4);
            float t = hSi + gB.y;
            t = fmaf(fyi, gA.x, t);
            t = fmaf(fxi, gA.y, t);
            t = fmaf(fri, gA.z, t);
            t = fmaf(fgi, gA.w, t);
            t = fmaf(fbi, gB.x, t);
            float k = exp2f(t);               // features pre-scaled: == exp(-0.5 d^2)
            const float* op = sow + jj * CP;
#pragma unroll
            for (int c = 0; c < CC; c++) acc[c] = fmaf(k, op[c], acc[c]);
        }
    }

    // cross-wave reduce: waves 1..3 dump acc, wave 0 sums and writes part
    __syncthreads();
    if (w > 0) {
        float* dst = smem + ((size_t)(w - 1) * 64 + lane) * CC;   // stride 21: conflict-free
#pragma unroll
        for (int c = 0; c < CC; c++) dst[c] = acc[c];
    }
    __syncthreads();
    if (w == 0) {
#pragma unroll
        for (int k = 0; k < 3; k++) {
            const float* s = smem + ((size_t)k * 64 + lane) * CC;
#pragma unroll
            for (int c = 0; c < CC; c++) acc[c] += s[c];
        }
        float* dst = part + ((size_t)blockIdx.y * NN + i) * CP;
#pragma unroll
        for (int q = 0; q < 6; q++) {
            float a0 = (q * 4 + 0 < CC) ? acc[q * 4 + 0] : 0.0f;
            float a1 = (q * 4 + 1 < CC) ? acc[q * 4 + 1] : 0.0f;
            float a2 = (q * 4 + 2 < CC) ? acc[q * 4 + 2] : 0.0f;
            float a3 = (q * 4 + 3 < CC) ? acc[q * 4 + 3] : 0.0f;
            ((float4*)dst)[q] = make_float4(a0, a1, a2, a3);
        }
    }
}

// ---------------- separable smoothness conv (exact, full width) -----------
__global__ __launch_bounds__(256) void smo_y_kernel(const float* __restrict__ src,
                                                    float* __restrict__ dst) {
    __shared__ float wt[2 * HH - 1];
    int tid = threadIdx.x;
    if (tid < 2 * HH - 1) {
        float d = (float)(tid - (HH - 1));
        wt[tid] = __expf(d * d * (-1.0f / 18.0f));
    }
    __syncthreads();
    int id = blockIdx.x * 256 + tid;       // c*NN + y*WW + x
    int c = id / NN;
    int rem = id - c * NN;
    int y = rem / WW;
    int x = rem - y * WW;
    const float* s = src + (size_t)c * NN + x;
    float a = 0.0f;
    for (int yp = 0; yp < HH; yp++) a = fmaf(wt[yp - y + (HH - 1)], s[yp * WW], a);
    dst[id] = a;
}

__global__ __launch_bounds__(256) void smo_x_kernel(const float* __restrict__ src,
                                                    float* __restrict__ dst) {
    __shared__ float wt[2 * HH - 1];
    int tid = threadIdx.x;
    if (tid < 2 * HH - 1) {
        float d = (float)(tid - (HH - 1));
        wt[tid] = __expf(d * d * (-1.0f / 18.0f));
    }
    __syncthreads();
    int id = blockIdx.x * 256 + tid;
    int c = id / NN;
    int rem = id - c * NN;
    int y = rem / WW;
    int x = rem - y * WW;
    const float* s = src + (size_t)c * NN + y * WW;
    float a = 0.0f;
    for (int xp = 0; xp < WW; xp++) a = fmaf(wt[xp - x + (HH - 1)], s[xp], a);
    dst[id] = a;
}

// ---------------- reduce partials + mu transform + softmax ----------------
__global__ __launch_bounds__(256) void combine_kernel(const float* __restrict__ part,
                                                      const float* __restrict__ smo,
                                                      const float* __restrict__ mu,
                                                      float* __restrict__ unary,
                                                      float* __restrict__ out_nc,
                                                      float* __restrict__ out_cn) {
    __shared__ float muL[CC * CC];
    int tid = threadIdx.x;
    for (int u = tid; u < CC * CC; u += 256) muL[u] = mu[u];
    __syncthreads();
    int n = blockIdx.x * 256 + tid;
    float app[CP];
#pragma unroll
    for (int c = 0; c < CP; c++) app[c] = 0.0f;
    for (int k = 0; k < JS; k++) {
        const float4* p4 = (const float4*)(part + ((size_t)k * NN + n) * CP);
#pragma unroll
        for (int q = 0; q < 6; q++) {
            float4 v = p4[q];
            app[q * 4 + 0] += v.x;
            app[q * 4 + 1] += v.y;
            app[q * 4 + 2] += v.z;
            app[q * 4 + 3] += v.w;
        }
    }
    float pin[CC];
#pragma unroll
    for (int c = 0; c < CC; c++) pin[c] = 10.0f * app[c] + 3.0f * smo[c * NN + n];
    float pout[CC];
#pragma unroll
    for (int j = 0; j < CC; j++) pout[j] = 0.0f;
#pragma unroll
    for (int i2 = 0; i2 < CC; i2++) {
        float v = pin[i2];
#pragma unroll
        for (int j = 0; j < CC; j++) pout[j] = fmaf(v, muL[i2 * CC + j], pout[j]);
    }
    float u[CC], p[CC];
    float m = -1e30f;
#pragma unroll
    for (int c = 0; c < CC; c++) {
        u[c] = unary[n * CP + c] + pout[c];
        m = fmaxf(m, u[c]);
    }
    float s = 0.0f;
#pragma unroll
    for (int c = 0; c < CC; c++) { p[c] = __expf(u[c] - m); s += p[c]; }
    float inv = 1.0f / s;
#pragma unroll
    for (int c = 0; c < CC; c++) p[c] *= inv;
#pragma unroll
    for (int c = 0; c < CC; c++) {
        unary[n * CP + c] = u[c];
        out_nc[n * CP + c] = p[c];
        out_cn[c * NN + n] = p[c];
    }
}

extern "C" void kernel_launch(void* const* d_in, const int* in_sizes, int n_in,
                              void* d_out, int out_size, void* d_ws, size_t ws_size,
                              hipStream_t stream) {
    const float* x = (const float*)d_in[0];     // (3,96,96)
    const float* yhat = (const float*)d_in[1];  // (21,96,96)
    const float* mu = (const float*)d_in[2];    // (21,21)
    float* out = (float*)d_out;                 // (21,96,96) — used as out_cn
    float* ws = (float*)d_ws;

    float* feat   = ws;                         // 8*N      = 73728
    float* out_nc = ws + 73728;                 // 24*N     = 221184
    float* unary  = ws + 294912;                // 24*N
    float* smo    = ws + 516096;                // 21*N     = 193536
    float* tmp    = ws + 709632;                // 21*N
    float* part   = ws + 903168;                // JS*24*N  = 3538944

    feat_kernel<<<NN / 256, 256, 0, stream>>>(x, feat);
    init_kernel<<<NN / 256, 256, 0, stream>>>(yhat, unary, out_nc, out);

    for (int it = 0; it < 5; it++) {
        bilateral_kernel<<<dim3(NN / 64, JS), 256, 0, stream>>>(feat, out_nc, part);
        smo_y_kernel<<<CC * NN / 256, 256, 0, stream>>>(out, tmp);
        smo_x_kernel<<<CC * NN / 256, 256, 0, stream>>>(tmp, smo);
        combine_kernel<<<NN / 256, 256, 0, stream>>>(part, smo, mu, unary, out_nc, out);
    }
}

// Round 5
// 367.701 us; speedup vs baseline: 2.1569x; 1.5299x over previous
//
#include <hip/hip_runtime.h>
#include <math.h>

// DenseCRF mean-field on MI355X. N=9216, C=21, 5 iters.
// R5: same as R4 (split-f16 3-MFMA bilateral) with cvt_pkrtz type fix.
// K = Kh+Kl, OUT = Oh+Ol, acc += Kh*Oh + Kl*Oh + Kh*Ol  (error ~2^-20).

#define NN 9216
#define CC 21
#define HH 96
#define WW 96
#define CP 24            // unary channel stride (f32)
#define JS2 8            // j-slices
#define NJ2 (NN / JS2)   // 1152 j per slice
#define WQ (NJ2 / 4)     // 288 j per wave
#define TJB 96           // j per staging round (3 K-steps of 32)
#define OST 104          // LDS out^T row stride in f16

typedef _Float16 half8 __attribute__((ext_vector_type(8)));
typedef __fp16 fp16x2 __attribute__((ext_vector_type(2)));
typedef float f32x4 __attribute__((ext_vector_type(4)));

// ---------------- features: [n][8] = (fy..fb)*1/(sig*sqrt(ln2)), -0.5*||f||^2
__global__ __launch_bounds__(256) void feat_kernel(const float* __restrict__ x,
                                                   float* __restrict__ feat) {
    int n = blockIdx.x * 256 + threadIdx.x;
    int y = n / WW, xx = n - y * WW;
    const float inv_sqrt_ln2 = 1.2011224087864498f;
    float sp = inv_sqrt_ln2 / 30.0f;
    float sc = inv_sqrt_ln2 * 10.0f;
    float fy = (float)y * sp;
    float fx = (float)xx * sp;
    float fr = x[0 * NN + n] * sc;
    float fg = x[1 * NN + n] * sc;
    float fb = x[2 * NN + n] * sc;
    float S = fy * fy + fx * fx + fr * fr + fg * fg + fb * fb;
    float4* f4 = (float4*)(feat + (size_t)n * 8);
    f4[0] = make_float4(fy, fx, fr, fg);
    f4[1] = make_float4(fb, -0.5f * S, 0.0f, 0.0f);
}

// ---------------- initial softmax -> unary, out hi/lo (f16 c-major), out_cn
__global__ __launch_bounds__(256) void init_kernel(const float* __restrict__ yhat,
                                                   float* __restrict__ unary,
                                                   _Float16* __restrict__ out_hi,
                                                   _Float16* __restrict__ out_lo,
                                                   float* __restrict__ out_cn) {
    int n = blockIdx.x * 256 + threadIdx.x;
    float u[CC], p[CC];
    float m = -1e30f;
#pragma unroll
    for (int c = 0; c < CC; c++) { u[c] = yhat[c * NN + n]; m = fmaxf(m, u[c]); }
    float s = 0.0f;
#pragma unroll
    for (int c = 0; c < CC; c++) { p[c] = __expf(u[c] - m); s += p[c]; }
    float inv = 1.0f / s;
#pragma unroll
    for (int c = 0; c < CC; c++) p[c] *= inv;
#pragma unroll
    for (int c = 0; c < CC; c++) {
        unary[n * CP + c] = u[c];
        _Float16 ph = (_Float16)p[c];
        out_hi[(size_t)c * NN + n] = ph;
        out_lo[(size_t)c * NN + n] = (_Float16)(p[c] - (float)ph);
        out_cn[c * NN + n] = p[c];
    }
#pragma unroll
    for (int c = CC; c < CP; c++) {
        unary[n * CP + c] = 0.0f;
        out_hi[(size_t)c * NN + n] = (_Float16)0.0f;
        out_lo[(size_t)c * NN + n] = (_Float16)0.0f;
    }
}

// ---------------- bilateral via split-f16 MFMA ----------------------------
// grid (NN/64=144, JS2=8). Block: 64 i's (4 i-tiles of 16 per wave); wave w
// handles j-quarter w of the block's slice. K computed on the fly.
__global__ __launch_bounds__(256, 3) void bilateral_mfma(const float* __restrict__ feat,
                                                         const _Float16* __restrict__ out_hi,
                                                         const _Float16* __restrict__ out_lo,
                                                         float* __restrict__ part) {
    __shared__ float smemf[13056];                      // 52224 B
    float* sfeat = smemf;                               // [4][96*8] f32 = 3072
    _Float16* sh_ = (_Float16*)(smemf + 3072);          // [4][24*OST] f16 hi
    _Float16* sl_ = (_Float16*)(smemf + 8064);          // [4][24*OST] f16 lo

    const int tid = threadIdx.x;
    const int lane = tid & 63;
    const int w = tid >> 6;
    const int r = lane & 15;       // A-row / B-col / D-col index
    const int g = lane >> 4;       // k-group
    const int i0 = blockIdx.x * 64;
    const int jslice = blockIdx.y * NJ2;

    float fi0[4], fi1[4], fi2[4], fi3[4], fi4[4], hsi[4];
#pragma unroll
    for (int m = 0; m < 4; ++m) {
        const float* fp = feat + (size_t)(i0 + m * 16 + r) * 8;
        float4 A = *(const float4*)fp;
        float2 B = *(const float2*)(fp + 4);
        fi0[m] = A.x; fi1[m] = A.y; fi2[m] = A.z; fi3[m] = A.w;
        fi4[m] = B.x; hsi[m] = B.y;
    }

    f32x4 acc[4][2];
#pragma unroll
    for (int m = 0; m < 4; ++m) { acc[m][0] = (f32x4)0.0f; acc[m][1] = (f32x4)0.0f; }

#pragma unroll 1
    for (int rd = 0; rd < WQ / TJB; ++rd) {     // 3 rounds
        __syncthreads();
        // stage j-features: 4 regions x 96 j x 8 f32 (768 float4)
        for (int v = tid; v < 768; v += 256) {
            int rw = v / 192, u = v - rw * 192;
            ((float4*)(sfeat + rw * (TJB * 8)))[u] =
                ((const float4*)(feat + (size_t)(jslice + rw * WQ + rd * TJB) * 8))[u];
        }
        // stage out hi+lo: 4 regions x 24 c x 12 chunks each
        for (int v = tid; v < 1152; v += 256) {
            int rw = v / 288, u = v - rw * 288;
            int c = u / 12, j8 = u - c * 12;
            size_t src = (size_t)c * NN + jslice + rw * WQ + rd * TJB + j8 * 8;
            *(float4*)(sh_ + (size_t)rw * (24 * OST) + c * OST + j8 * 8) =
                *(const float4*)(out_hi + src);
            *(float4*)(sl_ + (size_t)rw * (24 * OST) + c * OST + j8 * 8) =
                *(const float4*)(out_lo + src);
        }
        __syncthreads();

        const float* sfw = sfeat + w * (TJB * 8);
        const _Float16* shw = sh_ + (size_t)w * (24 * OST);
        const _Float16* slw = sl_ + (size_t)w * (24 * OST);
        const int r2 = (r < 8) ? (16 + r) : 23;   // clamp to zero row
#pragma unroll 1
        for (int ks = 0; ks < 3; ++ks) {
            int jb = ks * 32 + g * 8;          // this lane's 8 j's (k-dim)
            float4 fa[8]; float2 fb[8];
#pragma unroll
            for (int t = 0; t < 8; ++t) {
                const float* jp = sfw + (jb + t) * 8;
                fa[t] = *(const float4*)jp;
                fb[t] = *(const float2*)(jp + 4);
            }
            half8 b0h = *(const half8*)(shw + r * OST + jb);
            half8 b0l = *(const half8*)(slw + r * OST + jb);
            half8 b1h = *(const half8*)(shw + r2 * OST + jb);
            half8 b1l = *(const half8*)(slw + r2 * OST + jb);
#pragma unroll
            for (int m = 0; m < 4; ++m) {
                half8 afh, afl;
#pragma unroll
                for (int t2 = 0; t2 < 4; ++t2) {
                    float d0 = hsi[m] + fb[2 * t2].y;
                    d0 = fmaf(fi0[m], fa[2 * t2].x, d0);
                    d0 = fmaf(fi1[m], fa[2 * t2].y, d0);
                    d0 = fmaf(fi2[m], fa[2 * t2].z, d0);
                    d0 = fmaf(fi3[m], fa[2 * t2].w, d0);
                    d0 = fmaf(fi4[m], fb[2 * t2].x, d0);
                    float d1 = hsi[m] + fb[2 * t2 + 1].y;
                    d1 = fmaf(fi0[m], fa[2 * t2 + 1].x, d1);
                    d1 = fmaf(fi1[m], fa[2 * t2 + 1].y, d1);
                    d1 = fmaf(fi2[m], fa[2 * t2 + 1].z, d1);
                    d1 = fmaf(fi3[m], fa[2 * t2 + 1].w, d1);
                    d1 = fmaf(fi4[m], fb[2 * t2 + 1].x, d1);
                    float k0 = __builtin_amdgcn_exp2f(d0);
                    float k1 = __builtin_amdgcn_exp2f(d1);
                    fp16x2 kh = __builtin_amdgcn_cvt_pkrtz(k0, k1);
                    fp16x2 kl = __builtin_amdgcn_cvt_pkrtz(k0 - (float)kh.x,
                                                           k1 - (float)kh.y);
                    afh[2 * t2] = (_Float16)kh.x; afh[2 * t2 + 1] = (_Float16)kh.y;
                    afl[2 * t2] = (_Float16)kl.x; afl[2 * t2 + 1] = (_Float16)kl.y;
                }
                acc[m][0] = __builtin_amdgcn_mfma_f32_16x16x32_f16(afh, b0h, acc[m][0], 0, 0, 0);
                acc[m][0] = __builtin_amdgcn_mfma_f32_16x16x32_f16(afl, b0h, acc[m][0], 0, 0, 0);
                acc[m][0] = __builtin_amdgcn_mfma_f32_16x16x32_f16(afh, b0l, acc[m][0], 0, 0, 0);
                acc[m][1] = __builtin_amdgcn_mfma_f32_16x16x32_f16(afh, b1h, acc[m][1], 0, 0, 0);
                acc[m][1] = __builtin_amdgcn_mfma_f32_16x16x32_f16(afl, b1h, acc[m][1], 0, 0, 0);
                acc[m][1] = __builtin_amdgcn_mfma_f32_16x16x32_f16(afh, b1l, acc[m][1], 0, 0, 0);
            }
        }
    }

    // cross-wave reduce: all waves dump acc (stride 36), wave w owns i-tile w
    __syncthreads();
    {
        float* dst = smemf + (size_t)(w * 64 + lane) * 36;
#pragma unroll
        for (int m = 0; m < 4; ++m) {
            *(f32x4*)(dst + m * 8 + 0) = acc[m][0];
            *(f32x4*)(dst + m * 8 + 4) = acc[m][1];
        }
    }
    __syncthreads();
    f32x4 s0 = (f32x4)0.0f, s1 = (f32x4)0.0f;
#pragma unroll
    for (int k = 0; k < 4; ++k) {
        const float* src = smemf + (size_t)(k * 64 + lane) * 36 + w * 8;
        s0 += *(const f32x4*)(src);
        s1 += *(const f32x4*)(src + 4);
    }
    {
        // D layout: i = i0 + w*16 + g*4 + q, class = {r, 16+r}
        float* pb = part + ((size_t)blockIdx.y * NN + i0 + w * 16 + g * 4) * 32 + r;
#pragma unroll
        for (int q = 0; q < 4; ++q) {
            pb[q * 32] = s0[q];
            pb[q * 32 + 16] = s1[q];
        }
    }
}

// ---------------- separable smoothness conv (exact, full width) -----------
__global__ __launch_bounds__(256) void smo_y_kernel(const float* __restrict__ src,
                                                    float* __restrict__ dst) {
    __shared__ float wt[2 * HH - 1];
    int tid = threadIdx.x;
    if (tid < 2 * HH - 1) {
        float d = (float)(tid - (HH - 1));
        wt[tid] = __expf(d * d * (-1.0f / 18.0f));
    }
    __syncthreads();
    int id = blockIdx.x * 256 + tid;       // c*NN + y*WW + x
    int c = id / NN;
    int rem = id - c * NN;
    int y = rem / WW;
    int x = rem - y * WW;
    const float* s = src + (size_t)c * NN + x;
    float a = 0.0f;
    for (int yp = 0; yp < HH; yp++) a = fmaf(wt[yp - y + (HH - 1)], s[yp * WW], a);
    dst[id] = a;
}

__global__ __launch_bounds__(256) void smo_x_kernel(const float* __restrict__ src,
                                                    float* __restrict__ dst) {
    __shared__ float wt[2 * HH - 1];
    int tid = threadIdx.x;
    if (tid < 2 * HH - 1) {
        float d = (float)(tid - (HH - 1));
        wt[tid] = __expf(d * d * (-1.0f / 18.0f));
    }
    __syncthreads();
    int id = blockIdx.x * 256 + tid;
    int c = id / NN;
    int rem = id - c * NN;
    int y = rem / WW;
    int x = rem - y * WW;
    const float* s = src + (size_t)c * NN + y * WW;
    float a = 0.0f;
    for (int xp = 0; xp < WW; xp++) a = fmaf(wt[xp - x + (HH - 1)], s[xp], a);
    dst[id] = a;
}

// ---------------- reduce partials + mu transform + softmax ----------------
__global__ __launch_bounds__(256) void combine_kernel(const float* __restrict__ part,
                                                      const float* __restrict__ smo,
                                                      const float* __restrict__ mu,
                                                      float* __restrict__ unary,
                                                      _Float16* __restrict__ out_hi,
                                                      _Float16* __restrict__ out_lo,
                                                      float* __restrict__ out_cn) {
    __shared__ float muL[CC * CC];
    int tid = threadIdx.x;
    for (int u = tid; u < CC * CC; u += 256) muL[u] = mu[u];
    __syncthreads();
    int n = blockIdx.x * 256 + tid;
    float app[32];
#pragma unroll
    for (int c = 0; c < 32; c++) app[c] = 0.0f;
    for (int k = 0; k < JS2; k++) {
        const float4* p4 = (const float4*)(part + ((size_t)k * NN + n) * 32);
#pragma unroll
        for (int q = 0; q < 8; q++) {
            float4 v = p4[q];
            app[q * 4 + 0] += v.x;
            app[q * 4 + 1] += v.y;
            app[q * 4 + 2] += v.z;
            app[q * 4 + 3] += v.w;
        }
    }
    float pin[CC];
#pragma unroll
    for (int c = 0; c < CC; c++) pin[c] = 10.0f * app[c] + 3.0f * smo[c * NN + n];
    float pout[CC];
#pragma unroll
    for (int j = 0; j < CC; j++) pout[j] = 0.0f;
#pragma unroll
    for (int i2 = 0; i2 < CC; i2++) {
        float v = pin[i2];
#pragma unroll
        for (int j = 0; j < CC; j++) pout[j] = fmaf(v, muL[i2 * CC + j], pout[j]);
    }
    float u[CC], p[CC];
    float m = -1e30f;
#pragma unroll
    for (int c = 0; c < CC; c++) {
        u[c] = unary[n * CP + c] + pout[c];
        m = fmaxf(m, u[c]);
    }
    float s = 0.0f;
#pragma unroll
    for (int c = 0; c < CC; c++) { p[c] = __expf(u[c] - m); s += p[c]; }
    float inv = 1.0f / s;
#pragma unroll
    for (int c = 0; c < CC; c++) p[c] *= inv;
#pragma unroll
    for (int c = 0; c < CC; c++) {
        unary[n * CP + c] = u[c];
        _Float16 ph = (_Float16)p[c];
        out_hi[(size_t)c * NN + n] = ph;
        out_lo[(size_t)c * NN + n] = (_Float16)(p[c] - (float)ph);
        out_cn[c * NN + n] = p[c];
    }
}

extern "C" void kernel_launch(void* const* d_in, const int* in_sizes, int n_in,
                              void* d_out, int out_size, void* d_ws, size_t ws_size,
                              hipStream_t stream) {
    const float* x = (const float*)d_in[0];     // (3,96,96)
    const float* yhat = (const float*)d_in[1];  // (21,96,96)
    const float* mu = (const float*)d_in[2];    // (21,21)
    float* out = (float*)d_out;                 // (21,96,96) c-major probs
    float* ws = (float*)d_ws;

    float*     feat   = ws;                         // 8*N            = 73728 f32
    _Float16*  out_hi = (_Float16*)(ws + 73728);    // 24*N f16       = 110592 f32-eq
    _Float16*  out_lo = (_Float16*)(ws + 184320);   // 24*N f16       = 110592 f32-eq
    float*     unary  = ws + 294912;                // 24*N           = 221184
    float*     smo    = ws + 516096;                // 21*N           = 193536
    float*     tmp    = ws + 709632;                // 21*N           = 193536
    float*     part   = ws + 903168;                // JS2*N*32       = 2359296 (~13MB total)

    feat_kernel<<<NN / 256, 256, 0, stream>>>(x, feat);
    init_kernel<<<NN / 256, 256, 0, stream>>>(yhat, unary, out_hi, out_lo, out);

    for (int it = 0; it < 5; it++) {
        bilateral_mfma<<<dim3(NN / 64, JS2), 256, 0, stream>>>(feat, out_hi, out_lo, part);
        smo_y_kernel<<<CC * NN / 256, 256, 0, stream>>>(out, tmp);
        smo_x_kernel<<<CC * NN / 256, 256, 0, stream>>>(tmp, smo);
        combine_kernel<<<NN / 256, 256, 0, stream>>>(part, smo, mu, unary, out_hi, out_lo, out);
    }
}